// Round 4
// baseline (8047.998 us; speedup 1.0000x reference)
//
#include <hip/hip_runtime.h>
#include <hip/hip_cooperative_groups.h>

// LSTM: B=1024, T=128, I=128, H=1024, O=64
// R3: persistent cooperative kernel. W held in VGPRs (144 regs/wave of
// B-fragments) across ALL 128 timesteps -> zero W re-fetch (was 1.2 GB L2
// traffic). Per step: stage A=[x_t|h] tiles to LDS (BK=128, dbuf, unrolled),
// 288 MFMAs/wave, in-wave gate gather via shfl_xor, grid.sync().
// Carried: XOR-swizzled LDS staging, MFMA proj with hi/lo bf16 w_fc.

#define B_DIM 1024
#define H_DIM 1024
#define I_DIM 128
#define T_DIM 128
#define XROW  (T_DIM * I_DIM)   // 16384
#define KDIM  (I_DIM + H_DIM)   // 1152
#define NCHUNK 36               // K chunks of 32
#define O_DIM 64

typedef float f32x4 __attribute__((ext_vector_type(4)));
typedef short bf16x8 __attribute__((ext_vector_type(8)));
typedef unsigned short u16x8 __attribute__((ext_vector_type(8)));

__device__ __forceinline__ unsigned short f2bf(float f) {
    union { float f; unsigned int u; } v; v.f = f;
    unsigned int r = v.u + 0x7fffu + ((v.u >> 16) & 1u);  // RNE
    return (unsigned short)(r >> 16);
}
__device__ __forceinline__ float bf2f(unsigned short b) {
    union { unsigned int u; float f; } v; v.u = ((unsigned int)b) << 16;
    return v.f;
}
__device__ __forceinline__ float sigm(float x) { return 1.f / (1.f + __expf(-x)); }
__device__ __forceinline__ float tanh_fast(float x) { return 2.f / (1.f + __expf(-2.f * x)) - 1.f; }

// ---- prep: fp32 x -> bf16 ----
__global__ void conv_x(const float* __restrict__ x, unsigned short* __restrict__ xb) {
    size_t i = ((size_t)blockIdx.x * 256 + threadIdx.x) * 8;
    float4 v0 = *(const float4*)(x + i);
    float4 v1 = *(const float4*)(x + i + 4);
    u16x8 o;
    o[0] = f2bf(v0.x); o[1] = f2bf(v0.y); o[2] = f2bf(v0.z); o[3] = f2bf(v0.w);
    o[4] = f2bf(v1.x); o[5] = f2bf(v1.y); o[6] = f2bf(v1.z); o[7] = f2bf(v1.w);
    *(u16x8*)(xb + i) = o;
}

// ---- prep: W2 in B-fragment order + combined bias ----
// N-order n: nb=n>>7, wn=(n>>4)&7, gate=(n>>2)&3, ju=n&3
//   -> orig gate row = gate*1024 + nb*32 + wn*4 + ju
// W2 element (chunk c, n, q, j) = Worig[orig(n)][c*32 + q*8 + j]
__global__ void build_w2(const float* __restrict__ w_ih, const float* __restrict__ w_hh,
                         const float* __restrict__ b_ih, const float* __restrict__ b_hh,
                         unsigned short* __restrict__ W2, float* __restrict__ bias2) {
    int n = blockIdx.x;
    int nb = n >> 7, wn = (n >> 4) & 7, gate = (n >> 2) & 3, ju = n & 3;
    int orig = gate * 1024 + nb * 32 + wn * 4 + ju;
    for (int k = threadIdx.x; k < KDIM; k += 256) {
        float v = (k < I_DIM) ? w_ih[(size_t)orig * I_DIM + k]
                              : w_hh[(size_t)orig * H_DIM + (k - I_DIM)];
        int cch = k >> 5, q = (k >> 3) & 3, j = k & 7;
        W2[(size_t)cch * 131072 + (size_t)n * 32 + q * 8 + j] = f2bf(v);
    }
    if (threadIdx.x == 0) bias2[n] = b_ih[orig] + b_hh[orig];
}

// ---- prep: w_fc fp32 -> hi/lo bf16 pair ----
__global__ void conv_wfc(const float* __restrict__ w_fc,
                         unsigned short* __restrict__ whi,
                         unsigned short* __restrict__ wlo) {
    int i = blockIdx.x * 256 + threadIdx.x;
    float v = w_fc[i];
    unsigned short h = f2bf(v);
    whi[i] = h;
    wlo[i] = f2bf(v - bf2f(h));
}

__global__ void zero_hc(unsigned short* __restrict__ h0, float* __restrict__ c) {
    int idx = blockIdx.x * 256 + threadIdx.x;
    h0[idx] = 0;
    c[idx] = 0.f;
}

// ---- persistent LSTM: all 128 timesteps in one cooperative kernel ----
// grid (32 nb, 8 mb) x 512 threads = 8 waves; 1 block/CU.
// Wave wv owns N-cols nb*128+wv*16..+15 for all M=128 rows of the block.
// B-fragments (36 chunks x 4 VGPR) persist in registers for all steps.
__global__ __launch_bounds__(512, 2)
void lstm_persist(const unsigned short* __restrict__ xb,
                  const unsigned short* __restrict__ W2,
                  const float* __restrict__ bias2,
                  unsigned short* __restrict__ h0,
                  unsigned short* __restrict__ h1,
                  float* __restrict__ c_st) {
    __shared__ __align__(16) unsigned short As[2 * 2 * 128 * 64];  // [buf][half][row][64] = 64 KB
    const int tid  = threadIdx.x;
    const int wv   = tid >> 6, lane = tid & 63;
    const int quad = lane >> 4, l16 = lane & 15;
    const int l7   = l16 & 7;
    const int nb   = blockIdx.x, mb = blockIdx.y;

    // load persistent B fragments (once)
    bf16x8 Breg[NCHUNK];
    {
        const size_t nbase = (size_t)(nb * 128 + wv * 16 + l16) * 32 + quad * 8;
#pragma unroll
        for (int cch = 0; cch < NCHUNK; ++cch)
            Breg[cch] = *(const bf16x8*)&W2[(size_t)cch * 131072 + nbase];
    }
    const float bn = bias2[nb * 128 + wv * 16 + l16];

    // staging lane geometry
    const int arow = lane >> 3;             // 0..7 local row
    const int ag   = lane & 7;              // physical 16B group
    const int cperm = ((ag ^ arow) << 3);   // swizzled source col (bf16 units)

    // epilogue lane geometry (active lanes l16<4)
    const int unit = nb * 32 + wv * 4 + (l16 & 3);

    cooperative_groups::grid_group grid = cooperative_groups::this_grid();

    for (int t = 0; t < T_DIM; ++t) {
        const unsigned short* hin = (t & 1) ? h1 : h0;
        unsigned short* hout      = (t & 1) ? h0 : h1;

        f32x4 acc[8];
#pragma unroll
        for (int mi = 0; mi < 8; ++mi) acc[mi] = f32x4{0.f, 0.f, 0.f, 0.f};

        // stage seg 0 (x_t) into buf 0
#pragma unroll
        for (int c4 = 0; c4 < 2; ++c4) {
#pragma unroll
            for (int hf = 0; hf < 2; ++hf) {
                const int row0 = wv * 16 + c4 * 8;
                const unsigned short* src =
                    xb + (size_t)(mb * 128 + row0 + arow) * XROW + t * I_DIM + hf * 64 + cperm;
                __builtin_amdgcn_global_load_lds(
                    (const __attribute__((address_space(1))) void*)src,
                    (__attribute__((address_space(3))) void*)(&As[((0 * 2 + hf) * 128 + row0) * 64]),
                    16, 0, 0);
            }
        }

#pragma unroll
        for (int s = 0; s < 9; ++s) {
            __syncthreads();  // stage(s) resident
            if (s < 8) {      // prefetch seg s+1 (h cols s*128..) into other buf
                const int nbuf = (s + 1) & 1;
#pragma unroll
                for (int c4 = 0; c4 < 2; ++c4) {
#pragma unroll
                    for (int hf = 0; hf < 2; ++hf) {
                        const int row0 = wv * 16 + c4 * 8;
                        const unsigned short* src =
                            hin + (size_t)(mb * 128 + row0 + arow) * H_DIM + s * 128 + hf * 64 + cperm;
                        __builtin_amdgcn_global_load_lds(
                            (const __attribute__((address_space(1))) void*)src,
                            (__attribute__((address_space(3))) void*)(&As[((nbuf * 2 + hf) * 128 + row0) * 64]),
                            16, 0, 0);
                    }
                }
            }
            const int bufc = s & 1;
#pragma unroll
            for (int cc = 0; cc < 4; ++cc) {
                const int kchunk = s * 4 + cc;
                const int half = cc >> 1, gb = (cc & 1) * 4;
                const int poff = (((gb + quad) ^ l7) << 3);
#pragma unroll
                for (int mi = 0; mi < 8; ++mi) {
                    const int row = mi * 16 + l16;
                    bf16x8 a = *(const bf16x8*)&As[((bufc * 2 + half) * 128 + row) * 64 + poff];
                    acc[mi] = __builtin_amdgcn_mfma_f32_16x16x32_bf16(a, Breg[kchunk], acc[mi], 0, 0, 0);
                }
            }
        }

        // epilogue: gather 4 gates (gate = l16>>2) via shfl_xor, cell update
#pragma unroll
        for (int mi = 0; mi < 8; ++mi) {
#pragma unroll
            for (int r = 0; r < 4; ++r) {
                float v  = acc[mi][r] + bn;
                float vf = __shfl_xor(v, 4);
                float vg = __shfl_xor(v, 8);
                float vo = __shfl_xor(v, 12);
                if (l16 < 4) {
                    const int row = mb * 128 + mi * 16 + quad * 4 + r;
                    const size_t idx = (size_t)row * H_DIM + unit;
                    const float cn = sigm(vf) * c_st[idx] + sigm(v) * tanh_fast(vg);
                    c_st[idx] = cn;
                    hout[idx] = f2bf(sigm(vo) * tanh_fast(cn));
                }
            }
        }

        grid.sync();  // h(t) visible device-wide before step t+1
    }
}

// ---- final projection via MFMA (hi/lo split w_fc) ----
__global__ __launch_bounds__(256, 1)
void proj_mfma(const unsigned short* __restrict__ h,
               const unsigned short* __restrict__ whi,
               const unsigned short* __restrict__ wlo,
               const float* __restrict__ b_fc,
               float* __restrict__ out) {
    const int wm = threadIdx.x >> 6, lane = threadIdx.x & 63;
    const int quad = lane >> 4, l16 = lane & 15;
    const int m0 = blockIdx.x * 64 + wm * 16;

    f32x4 acc[4];
#pragma unroll
    for (int ni = 0; ni < 4; ni++) acc[ni] = f32x4{0.f, 0.f, 0.f, 0.f};

    for (int k0 = 0; k0 < H_DIM; k0 += 32) {
        bf16x8 a = *(const bf16x8*)&h[(size_t)(m0 + l16) * H_DIM + k0 + quad * 8];
#pragma unroll
        for (int ni = 0; ni < 4; ni++) {
            const size_t wi = (size_t)(ni * 16 + l16) * H_DIM + k0 + quad * 8;
            bf16x8 bh = *(const bf16x8*)&whi[wi];
            bf16x8 bl = *(const bf16x8*)&wlo[wi];
            acc[ni] = __builtin_amdgcn_mfma_f32_16x16x32_bf16(a, bh, acc[ni], 0, 0, 0);
            acc[ni] = __builtin_amdgcn_mfma_f32_16x16x32_bf16(a, bl, acc[ni], 0, 0, 0);
        }
    }
#pragma unroll
    for (int ni = 0; ni < 4; ni++) {
        const float bfc = b_fc[ni * 16 + l16];
#pragma unroll
        for (int r = 0; r < 4; r++) {
            out[(size_t)(m0 + quad * 4 + r) * O_DIM + ni * 16 + l16] = acc[ni][r] + bfc;
        }
    }
}

extern "C" void kernel_launch(void* const* d_in, const int* in_sizes, int n_in,
                              void* d_out, int out_size, void* d_ws, size_t ws_size,
                              hipStream_t stream) {
    const float* x    = (const float*)d_in[0];
    const float* w_ih = (const float*)d_in[1];
    const float* w_hh = (const float*)d_in[2];
    const float* b_ih = (const float*)d_in[3];
    const float* b_hh = (const float*)d_in[4];
    const float* w_fc = (const float*)d_in[5];
    const float* b_fc = (const float*)d_in[6];
    float* out = (float*)d_out;

    char* ws = (char*)d_ws;
    size_t off = 0;
    unsigned short* xb  = (unsigned short*)(ws + off); off += (size_t)B_DIM * XROW * 2;
    unsigned short* W2  = (unsigned short*)(ws + off); off += (size_t)NCHUNK * 131072 * 2;
    float* bias2        = (float*)(ws + off);          off += (size_t)4 * H_DIM * 4;
    unsigned short* h0  = (unsigned short*)(ws + off); off += (size_t)B_DIM * H_DIM * 2;
    unsigned short* h1  = (unsigned short*)(ws + off); off += (size_t)B_DIM * H_DIM * 2;
    float* c            = (float*)(ws + off);          off += (size_t)B_DIM * H_DIM * 4;
    unsigned short* whi = (unsigned short*)(ws + off); off += (size_t)O_DIM * H_DIM * 2;
    unsigned short* wlo = (unsigned short*)(ws + off); off += (size_t)O_DIM * H_DIM * 2;

    conv_x<<<8192, 256, 0, stream>>>(x, xb);
    build_w2<<<4 * H_DIM, 256, 0, stream>>>(w_ih, w_hh, b_ih, b_hh, W2, bias2);
    conv_wfc<<<256, 256, 0, stream>>>(w_fc, whi, wlo);
    zero_hc<<<4096, 256, 0, stream>>>(h0, c);

    void* args[] = {(void*)&xb, (void*)&W2, (void*)&bias2,
                    (void*)&h0, (void*)&h1, (void*)&c};
    hipLaunchCooperativeKernel((void*)lstm_persist, dim3(32, 8), dim3(512),
                               args, 0, stream);

    // t=127 wrote h0
    proj_mfma<<<16, 256, 0, stream>>>(h0, whi, wlo, b_fc, out);
}